// Round 1
// baseline (1085.805 us; speedup 1.0000x reference)
//
#include <hip/hip_runtime.h>

// ---- shapes (hard-coded to this problem) ----
#define TT 64
#define SLOT 320          // OUT + ACT
#define CONCAT 1536       // IN + 4*SLOT
#define ROWPAD 1544       // CONCAT + 8 bf16 pad: row stride 3088B -> 4-bank skew, 2-way (free)

typedef __attribute__((ext_vector_type(8))) short bf16x8;
typedef __attribute__((ext_vector_type(4))) short short4v;
typedef __attribute__((ext_vector_type(4))) float float4v;

__device__ __forceinline__ short f2bf(float f) {
    union { float f; unsigned u; } v;
    v.f = f;
    unsigned r = v.u + 0x7fffu + ((v.u >> 16) & 1u);  // RNE
    return (short)(r >> 16);
}

// W (256 x 1536 fp32) -> bf16 in d_ws. Rewritten every call (d_ws is re-poisoned).
__global__ void wprep_kernel(const float* __restrict__ W, short* __restrict__ Wb) {
    int i = blockIdx.x * 256 + threadIdx.x;          // float4 index, 98304 total
    if (i < 98304) {
        float4v v = ((const float4v*)W)[i];
        short4v s;
        s.x = f2bf(v.x); s.y = f2bf(v.y); s.z = f2bf(v.z); s.w = f2bf(v.w);
        ((short4v*)Wb)[i] = s;
    }
}

// Persistent recurrence kernel: 64 WGs (16 b x 4 p-blocks), 16 sequences/WG,
// 4 waves/WG each owning 64 of the 256 outputs.
__global__ __launch_bounds__(256) void hist_kernel(
    const float* __restrict__ o,    // (B,T,P,256)
    const float* __restrict__ act,  // (B,T,P,64)
    const float* __restrict__ bias, // (256)
    const short* __restrict__ Wb,   // (256,1536) bf16 bits
    float* __restrict__ out)        // (B,T,P,256)
{
    __shared__ short x[16 * ROWPAD];   // 49408 B: per-seq row = [4 slots of z(256)+a(64)][o(256)][pad]

    const int tid  = threadIdx.x;
    const int wave = tid >> 6;
    const int lane = tid & 63;
    const int q    = lane >> 4;   // quad: k-sub-block of MFMA operands
    const int ln   = lane & 15;   // A-row (seq) / B-col (out) within tile
    const int bb   = blockIdx.x >> 2;
    const int p0   = (blockIdx.x & 3) << 4;

    // zero history region (cols 0..1279) of every row; o-region is overwritten each step
    for (int i = tid; i < 16 * 640; i += 256) {
        int row = i / 640, c = i % 640;
        *(float*)&x[row * ROWPAD + c * 2] = 0.f;
    }

    float bv[4];
#pragma unroll
    for (int tl = 0; tl < 4; ++tl) bv[tl] = bias[(wave << 6) + (tl << 4) + ln];

    // per-tile W row base (B-frag: lane ln reads W[n][cW + q*8 .. +7], 16B load)
    const short* wbase[4];
#pragma unroll
    for (int tl = 0; tl < 4; ++tl)
        wbase[tl] = Wb + (size_t)((wave << 6) + (tl << 4) + ln) * CONCAT + (q << 3);

    const int arow = ln * ROWPAD + (q << 3);   // A-frag: row ln, k-offset q*8

    for (int t = 0; t < TT; ++t) {
        // ---- stage o_t into LDS (bf16), grab a_t into regs ----
        const float4v* og = (const float4v*)(o   + (((size_t)bb * TT + t) * 64 + p0) * 256);
        const float4v* ag = (const float4v*)(act + (((size_t)bb * TT + t) * 64 + p0) * 64);
        float4v av = ag[tid];
#pragma unroll
        for (int c = 0; c < 4; ++c) {
            float4v ov = og[tid + c * 256];
            int f = (tid + c * 256) << 2;
            int row = f >> 8, col = f & 255;
            short4v s;
            s.x = f2bf(ov.x); s.y = f2bf(ov.y); s.z = f2bf(ov.z); s.w = f2bf(ov.w);
            *(short4v*)&x[row * ROWPAD + 1280 + col] = s;
        }
        __syncthreads();   // barrier1: o_t + prev-step z/a slot writes visible

        // physical slot base per logical history index h (h=3 newest = z_{t-1})
        int pbase[4];
#pragma unroll
        for (int h = 0; h < 4; ++h) pbase[h] = ((h + t) & 3) * SLOT;

        float4v acc0 = {0.f, 0.f, 0.f, 0.f};
        float4v acc1 = acc0, acc2 = acc0, acc3 = acc0;

#pragma unroll
        for (int kb = 0; kb < 48; ++kb) {
            int cW, cL;
            if (kb < 40) {
                const int h   = kb / 10;
                const int r   = kb % 10;
                const int off = (r < 8) ? (r << 5) : (256 + ((r - 8) << 5));
                cW = h * SLOT + off;        // logical (W) column
                cL = pbase[h] + off;        // physical (LDS) column
            } else {
                cW = 1280 + ((kb - 40) << 5);
                cL = cW;
            }
            bf16x8 af = *(const bf16x8*)&x[arow + cL];
            bf16x8 b0 = *(const bf16x8*)(wbase[0] + cW);
            bf16x8 b1 = *(const bf16x8*)(wbase[1] + cW);
            bf16x8 b2 = *(const bf16x8*)(wbase[2] + cW);
            bf16x8 b3 = *(const bf16x8*)(wbase[3] + cW);
            acc0 = __builtin_amdgcn_mfma_f32_16x16x32_bf16(af, b0, acc0, 0, 0, 0);
            acc1 = __builtin_amdgcn_mfma_f32_16x16x32_bf16(af, b1, acc1, 0, 0, 0);
            acc2 = __builtin_amdgcn_mfma_f32_16x16x32_bf16(af, b2, acc2, 0, 0, 0);
            acc3 = __builtin_amdgcn_mfma_f32_16x16x32_bf16(af, b3, acc3, 0, 0, 0);
        }
        __syncthreads();   // barrier2: everyone done reading slot (t&3) before we overwrite it

        // ---- epilogue: z_t -> global (fp32) + LDS slot t&3 (bf16); a_t -> LDS slot ----
        float* outp = out + (((size_t)bb * TT + t) * 64 + p0) * 256;
        const int pz = (t & 3) * SLOT;
        float4v accs[4] = {acc0, acc1, acc2, acc3};
#pragma unroll
        for (int tl = 0; tl < 4; ++tl) {
            const int n = (wave << 6) + (tl << 4) + ln;
#pragma unroll
            for (int r = 0; r < 4; ++r) {
                const int m = (q << 2) + r;          // C/D: row m = quad*4+reg, col n = lane&15
                float z = accs[tl][r] + bv[tl];
                outp[(size_t)m * 256 + n] = z;
                x[m * ROWPAD + pz + n] = f2bf(z);
            }
        }
        {
            const int f = tid << 2;
            const int row = f >> 6, col = f & 63;
            short4v s;
            s.x = f2bf(av.x); s.y = f2bf(av.y); s.z = f2bf(av.z); s.w = f2bf(av.w);
            *(short4v*)&x[row * ROWPAD + pz + 256 + col] = s;
        }
        // next iteration's barrier1 orders these writes before the next compute
    }
}

extern "C" void kernel_launch(void* const* d_in, const int* in_sizes, int n_in,
                              void* d_out, int out_size, void* d_ws, size_t ws_size,
                              hipStream_t stream) {
    const float* o  = (const float*)d_in[0];
    const float* a  = (const float*)d_in[1];
    const float* W  = (const float*)d_in[2];
    const float* b  = (const float*)d_in[3];
    short* Wb = (short*)d_ws;                         // 786432 B of workspace

    hipLaunchKernelGGL(wprep_kernel, dim3(384), dim3(256), 0, stream, W, Wb);
    hipLaunchKernelGGL(hist_kernel, dim3(64), dim3(256), 0, stream,
                       o, a, b, Wb, (float*)d_out);
}